// Round 17
// baseline (153.094 us; speedup 1.0000x reference)
//
#include <hip/hip_runtime.h>
#include <cstdint>
#include <cstddef>

typedef __bf16 bf16;
typedef __bf16 bf16x8 __attribute__((ext_vector_type(8)));
typedef __bf16 bf16x4 __attribute__((ext_vector_type(4)));
typedef float  f32x4  __attribute__((ext_vector_type(4)));

#define MFMA16(a, b, c) __builtin_amdgcn_mfma_f32_16x16x32_bf16(a, b, c, 0, 0, 0)

// async global->LDS, 16B per lane, dest = wave-uniform base + lane*16
__device__ __forceinline__ void gl2lds16(const bf16* g, bf16* l) {
  __builtin_amdgcn_global_load_lds(
      (const __attribute__((address_space(1))) void*)g,
      (__attribute__((address_space(3))) void*)l, 16, 0, 0);
}

// ---------------------------------------------------------------------------
// prep: f32 -> bf16 casts (x, W_in, W_out) + q_cls passthrough copy.
// ---------------------------------------------------------------------------
__device__ __forceinline__ void cvt4(const float* __restrict__ s, bf16* __restrict__ d) {
  f32x4 v = *(const f32x4*)s;
  bf16x4 o;
  o[0] = (bf16)v[0]; o[1] = (bf16)v[1]; o[2] = (bf16)v[2]; o[3] = (bf16)v[3];
  *(bf16x4*)d = o;
}

__global__ __launch_bounds__(256) void prep_kernel(
    const float* __restrict__ q, const float* __restrict__ win,
    const float* __restrict__ wout, float* __restrict__ out0,
    bf16* __restrict__ xb, bf16* __restrict__ wqb, bf16* __restrict__ wob) {
  long u = (long)blockIdx.x * 256 + threadIdx.x;
  const long NX4 = 1605632, NWQ4 = 196608, NWO4 = 65536, NQC4 = 1024;
  if (u < NX4) { cvt4(q + 4096 + u * 4, xb + u * 4); return; }
  u -= NX4;
  if (u < NWQ4) { cvt4(win + u * 4, wqb + u * 4); return; }
  u -= NWQ4;
  if (u < NWO4) { cvt4(wout + u * 4, wob + u * 4); return; }
  u -= NWO4;
  if (u < NQC4) { *(f32x4*)(out0 + u * 4) = *(const f32x4*)(q + u * 4); }
}

// ---------------------------------------------------------------------------
// GEMM2: C = A B^T + bias, f32 NT output. 128x128, BK=64, XOR-swizzle.
// ---------------------------------------------------------------------------
__global__ __launch_bounds__(256) void gemm_bt(
    const bf16* __restrict__ A, const bf16* __restrict__ Bm,
    const float* __restrict__ bias, float* __restrict__ Cf,
    int N, int K, long coff) {
  __shared__ bf16 As[128 * 64];
  __shared__ bf16 Bs[128 * 64];
  const int tid = threadIdx.x;
  const int wid = tid >> 6, lane = tid & 63;
  const int lr = lane & 15, lg = lane >> 4;

  const int nwg = gridDim.x * gridDim.y;
  const int orig = blockIdx.y * gridDim.x + blockIdx.x;
  const int cpx = nwg >> 3;
  const int swz = (orig & 7) * cpx + (orig >> 3);
  const int m0 = (swz / gridDim.x) * 128;
  const int n0 = (swz % gridDim.x) * 128;

  const int wr = wid >> 1, wc = wid & 1;
  const int slot = lane & 7, r8 = lane >> 3;
  const int chunk = slot ^ r8;
  const int x7 = lr & 7;

  f32x4 acc[4][4] = {};

  for (int kt = 0; kt < K; kt += 64) {
    __syncthreads();
#pragma unroll
    for (int j = 0; j < 4; ++j) {
      int blk = wid * 4 + j;
      int row = blk * 8 + r8;
      gl2lds16(A + (size_t)(m0 + row) * K + kt + chunk * 8, As + blk * 512);
      gl2lds16(Bm + (size_t)(n0 + row) * K + kt + chunk * 8, Bs + blk * 512);
    }
    __syncthreads();

#pragma unroll
    for (int kk = 0; kk < 2; ++kk) {
      bf16x8 af[4], bfr[4];
#pragma unroll
      for (int m = 0; m < 4; ++m)
        af[m] = *(const bf16x8*)(As + (wr * 64 + m * 16 + lr) * 64 +
                                 (((kk * 4 + lg) ^ x7) * 8));
#pragma unroll
      for (int n = 0; n < 4; ++n)
        bfr[n] = *(const bf16x8*)(Bs + (wc * 64 + n * 16 + lr) * 64 +
                                  (((kk * 4 + lg) ^ x7) * 8));
#pragma unroll
      for (int m = 0; m < 4; ++m)
#pragma unroll
        for (int n = 0; n < 4; ++n)
          acc[m][n] = MFMA16(af[m], bfr[n], acc[m][n]);
    }
  }

#pragma unroll
  for (int m = 0; m < 4; ++m) {
    int row = m0 + wr * 64 + m * 16 + lg * 4;
#pragma unroll
    for (int n = 0; n < 4; ++n) {
      int col = n0 + wc * 64 + n * 16 + lr;
      float bv = bias[col];
#pragma unroll
      for (int i = 0; i < 4; ++i)
        __builtin_nontemporal_store(
            acc[m][n][i] + bv, Cf + coff + (size_t)(row + i) * N + col);
    }
  }
}

// ---------------------------------------------------------------------------
// FUSED spatial. Phase 1 (QKV projection) now loads MFMA fragments DIRECTLY
// from global (L2/L3-resident xb/wqb): each lane holds 7 row-base pointers
// (4 X-rows for its q-tiles + 3 W-rows), per K-step loads bf16x8 at
// base + kt + lg*8 (exact fragment layout: row=lane&15, k=(lane>>4)*8+e).
// Removes ALL phase-1 LDS staging, ds_reads, and the 16 per-kt
// barrier+vmcnt(0) drains (r15/r16 showed MfmaUtil 17 / VALU 23 / BW 25% --
// the staging machinery, not any pipe, was the limiter). Phase-1 MFMA floor
// is ~1.6us/block; loop is now barrier-free and freely pipelined.
// Epilogue repack (acc -> Qb/Kl/Vt), slab export, and phase 2 unchanged.
// ---------------------------------------------------------------------------
__global__ __launch_bounds__(1024) void spatial_fused(
    const bf16* __restrict__ xb, const bf16* __restrict__ wqb,
    const float* __restrict__ bin, bf16* __restrict__ Qh,
    bf16* __restrict__ Kh, float* __restrict__ attn_out,
    bf16* __restrict__ outs) {
  __shared__ bf16 Kl[224 * 72];       // [k-row][72]
  __shared__ bf16 Vt[64 * 232];       // [d][k-row]
  __shared__ bf16 RB[40768];          // union: phase1 Qb / phase2 StgB
  bf16* const Qb  = RB;               // 13x16x72 = 14976 elems
  bf16* const StgB = RB;              // phase 2: 13x3136

  const int tid = threadIdx.x;
  const int wid = tid >> 6, lane = tid & 63;
  const int lr = lane & 15, lg = lane >> 4;
  const int batch = blockIdx.x;            // h*64 + bb*8 + ti
  const int h = batch >> 6;
  const int bb = (batch >> 3) & 7;
  const int ti = batch & 7;

  // zero Vt pad rows 208..223 (epilogue writes only rows <208)
  { int d = tid >> 4, r = 208 + (tid & 15); Vt[d * 232 + r] = (bf16)0.f; }

  // ================= phase 1: QKV projection, direct-L2 fragments =======
  const int qg = wid >> 2, ng = wid & 3;
  const int nfb = ng * 3;

  const bf16* xp[4];
#pragma unroll
  for (int qi = 0; qi < 4; ++qi) {
    int p = qg * 64 + qi * 16 + lr;
    if (p > 195) p = 195;               // pad rows: finite garbage, discarded
    xp[qi] = xb + ((size_t)(ti * 196 + p) * 8 + bb) * 512;
  }
  const bf16* wp[3];
#pragma unroll
  for (int nj = 0; nj < 3; ++nj) {
    int nf = nfb + nj;
    wp[nj] = wqb +
             (size_t)((nf >> 2) * 512 + h * 64 + (nf & 3) * 16 + lr) * 512;
  }

  f32x4 acc[4][3] = {};
#pragma unroll 4
  for (int kt = 0; kt < 512; kt += 32) {
    bf16x8 af[4], bfr[3];
#pragma unroll
    for (int qi = 0; qi < 4; ++qi)
      af[qi] = *(const bf16x8*)(xp[qi] + kt + lg * 8);
#pragma unroll
    for (int nj = 0; nj < 3; ++nj)
      bfr[nj] = *(const bf16x8*)(wp[nj] + kt + lg * 8);
#pragma unroll
    for (int nj = 0; nj < 3; ++nj)
#pragma unroll
      for (int qi = 0; qi < 4; ++qi)
        acc[qi][nj] = MFMA16(af[qi], bfr[nj], acc[qi][nj]);
  }

  // ---- epilogue: bias + repack to Kl/Vt/Qb (all writes guarded qt<13)
#pragma unroll
  for (int qi = 0; qi < 4; ++qi) {
    const int qtg = qg * 4 + qi;
    if (qtg < 13) {
#pragma unroll
      for (int nj = 0; nj < 3; ++nj) {
        const int nf = nfb + nj;             // wave-uniform
        const int strip = nf >> 2;
        float bv = bin[strip * 512 + h * 64 + (nf & 3) * 16 + lr];
        f32x4 a = acc[qi][nj];
#pragma unroll
        for (int i = 0; i < 4; ++i) a[i] += bv;
        if (strip == 0) {
          bf16* qb = Qb + qtg * 1152;
#pragma unroll
          for (int i = 0; i < 4; ++i)
            qb[(lg * 4 + i) * 72 + (nf & 3) * 16 + lr] = (bf16)a[i];
        } else if (strip == 1) {
#pragma unroll
          for (int i = 0; i < 4; ++i)
            Kl[(qtg * 16 + lg * 4 + i) * 72 + (nf & 3) * 16 + lr] =
                (bf16)a[i];
        } else {
          union { bf16x4 h4; uint2 u; } pk;
          pk.h4[0] = (bf16)a[0]; pk.h4[1] = (bf16)a[1];
          pk.h4[2] = (bf16)a[2]; pk.h4[3] = (bf16)a[3];
          int d = (nf & 3) * 16 + lr;
          *(uint2*)&Vt[d * 232 + qtg * 16 + lg * 4] = pk.u;
        }
      }
    }
  }
  __syncthreads();   // Kl/Vt/Qb complete

  // ---- aq read + slab export (cross-wave Qb/Kl reads)
  const int qt = wid;
  bf16x8 aq[2];
  if (qt < 13) {
    const bf16* qb = Qb + qt * 1152;
#pragma unroll
    for (int kk = 0; kk < 2; ++kk)
      aq[kk] = *(const bf16x8*)(qb + lr * 72 + kk * 32 + lg * 8);
    bf16* slabQ = Qh + (size_t)batch * 12544;
    bf16* slabK = Kh + (size_t)batch * 12544;
    const int erow = lane >> 3, eseg = lane & 7;
#pragma unroll
    for (int t = 0; t < 2; ++t) {
      int row = qt * 16 + t * 8 + erow;
      if (row < 196) {
        *(bf16x8*)(slabQ + row * 64 + eseg * 8) =
            *(const bf16x8*)(qb + (t * 8 + erow) * 72 + eseg * 8);
        *(bf16x8*)(slabK + row * 64 + eseg * 8) =
            *(const bf16x8*)(Kl + row * 72 + eseg * 8);
      }
    }
  }
  __syncthreads();   // Qb dead -> StgB may clobber

  // ================= phase 2: attention =================
  if (qt < 13) {
    const int q = qt * 16 + lr;

    f32x4 s[14] = {};
    __builtin_amdgcn_s_setprio(1);
#pragma unroll
    for (int nn = 0; nn < 14; ++nn) {
      const int krow = nn * 16 + lr;
      bf16x8 bk0 = *(const bf16x8*)&Kl[krow * 72 + lg * 8];
      bf16x8 bk1 = *(const bf16x8*)&Kl[krow * 72 + 32 + lg * 8];
      s[nn] = MFMA16(bk0, aq[0], s[nn]);
      s[nn] = MFMA16(bk1, aq[1], s[nn]);
    }
    __builtin_amdgcn_s_setprio(0);

#pragma unroll
    for (int nn = 0; nn < 14; ++nn) {
      bool pad = (nn * 16 + lg * 4 >= 196);
#pragma unroll
      for (int i = 0; i < 4; ++i)
        s[nn][i] = pad ? -1e30f : s[nn][i] * 0.125f;
    }

    float v = -1e30f;
#pragma unroll
    for (int nn = 0; nn < 14; ++nn)
#pragma unroll
      for (int i = 0; i < 4; ++i) v = fmaxf(v, s[nn][i]);
    v = fmaxf(v, __shfl_xor(v, 16));
    v = fmaxf(v, __shfl_xor(v, 32));
    float sum = 0.f;
#pragma unroll
    for (int nn = 0; nn < 14; ++nn)
#pragma unroll
      for (int i = 0; i < 4; ++i) {
        float e = __expf(s[nn][i] - v);
        s[nn][i] = e;
        sum += e;
      }
    sum += __shfl_xor(sum, 16);
    sum += __shfl_xor(sum, 32);
    const float rinv = 1.f / sum;

    bf16* const tile = StgB + qt * 3136;
    const int low = lr + 32 * (lg & 1);
    const int high = low + 16;
    const bool hiN = (lg >> 1) != 0;
    f32x4 o[4] = {};
#pragma unroll
    for (int kb = 0; kb < 7; ++kb) {
      uint32_t px[2], py[2];
#pragma unroll
      for (int t = 0; t < 2; ++t) {
        const int nn = 2 * kb + t;
        f32x4 sv;
#pragma unroll
        for (int i = 0; i < 4; ++i) sv[i] = s[nn][i] * rinv;
        union { bf16x4 h4; uint2 u; } pk;
        pk.h4[0] = (bf16)sv[0]; pk.h4[1] = (bf16)sv[1];
        pk.h4[2] = (bf16)sv[2]; pk.h4[3] = (bf16)sv[3];
        int kbase = nn * 16 + lg * 4;
        if (kbase < 196)
          *(uint2*)((char*)tile + lr * 392 + kbase * 2) = pk.u;
        px[t] = pk.u.x; py[t] = pk.u.y;
      }
      uint32_t a0x = __shfl((int)px[0], low);
      uint32_t a0y = __shfl((int)py[0], low);
      uint32_t a1x = __shfl((int)px[1], low);
      uint32_t a1y = __shfl((int)py[1], low);
      uint32_t b0x = __shfl((int)px[0], high);
      uint32_t b0y = __shfl((int)py[0], high);
      uint32_t b1x = __shfl((int)px[1], high);
      uint32_t b1y = __shfl((int)py[1], high);
      union { uint32_t u[4]; bf16x8 h8; } pa;
      pa.u[0] = hiN ? a1x : a0x;
      pa.u[1] = hiN ? a1y : a0y;
      pa.u[2] = hiN ? b1x : b0x;
      pa.u[3] = hiN ? b1y : b0y;
      __builtin_amdgcn_s_setprio(1);
#pragma unroll
      for (int nd = 0; nd < 4; ++nd) {
        bf16x8 vb = *(const bf16x8*)&Vt[(nd * 16 + lr) * 232 + kb * 32 + lg * 8];
        o[nd] = MFMA16(pa.h8, vb, o[nd]);
      }
      __builtin_amdgcn_s_setprio(0);
    }

    // write out_s in v_t layout [h][bb][p][ti][d]
    {
      const int hb8 = batch >> 3;
#pragma unroll
      for (int i = 0; i < 4; ++i) {
        int p = qt * 16 + lg * 4 + i;
        if (p < 196) {
#pragma unroll
          for (int nd = 0; nd < 4; ++nd) {
            int d = nd * 16 + lr;
            outs[(((size_t)(hb8 * 196 + p)) * 8 + ti) * 64 + d] =
                (bf16)o[nd][i];
          }
        }
      }
    }

    // aligned copy-out: LDS bf16 stripe -> global f32 (exact bit expand)
    {
      const int vbytes = (qt == 12) ? 3136 : 12544;
      char* dst = (char*)(attn_out + (size_t)batch * 38416 + qt * 3136);
      const char* src = (const char*)tile;
#pragma unroll
      for (int j = 0; j < 13; ++j) {
        int x = j * 1024 + lane * 16;
        if (x < vbytes) {
          uint2 u = *(const uint2*)(src + (x >> 1));
          union { uint32_t b; float f; } c0, c1, c2, c3;
          c0.b = (u.x & 0xffffu) << 16; c1.b = u.x & 0xffff0000u;
          c2.b = (u.y & 0xffffu) << 16; c3.b = u.y & 0xffff0000u;
          f32x4 ov; ov[0] = c0.f; ov[1] = c1.f; ov[2] = c2.f; ov[3] = c3.f;
          *(f32x4*)(dst + x) = ov;
        }
      }
    }
  }
}

// ---------------------------------------------------------------------------
// Temporal attention: 1 wave per (h, bb, p) batch; t=8, dh=64.
// ---------------------------------------------------------------------------
__global__ __launch_bounds__(256) void temporal_attn(
    const bf16* __restrict__ Qh, const bf16* __restrict__ Kh,
    const bf16* __restrict__ outs, bf16* __restrict__ outt) {
  __shared__ bf16 Ql[4][8][72];
  __shared__ bf16 Kc[4][8][72];
  __shared__ bf16 Vl[4][8][64];
  __shared__ float Ps[4][8][8];

  const int tid = threadIdx.x, wid = tid >> 6, lane = tid & 63;
  const int batch = blockIdx.x * 4 + wid;  // (h*8+bb)*196 + p
  const int p = batch % 196;
  const int hb = batch / 196;
  const int bb = hb & 7, h = hb >> 3;

  const int ri = lane >> 3;
  const int c8 = lane & 7;
  {
    size_t so = ((size_t)(h * 64 + bb * 8 + ri)) * 12544 + p * 64 + c8 * 8;
    *(bf16x8*)&Ql[wid][ri][c8 * 8] = *(const bf16x8*)(Qh + so);
    *(bf16x8*)&Kc[wid][ri][c8 * 8] = *(const bf16x8*)(Kh + so);
    *(bf16x8*)&Vl[wid][ri][c8 * 8] =
        *(const bf16x8*)(outs + ((size_t)batch * 8 + ri) * 64 + c8 * 8);
  }
  __syncthreads();

  float s = 0.f;
#pragma unroll
  for (int d = 0; d < 64; d += 8) {
    bf16x8 qv = *(const bf16x8*)&Ql[wid][ri][d];
    bf16x8 kv = *(const bf16x8*)&Kc[wid][c8][d];
#pragma unroll
    for (int e = 0; e < 8; ++e) s += (float)qv[e] * (float)kv[e];
  }
  s *= 0.125f;
  float mxv = s;
#pragma unroll
  for (int d2 = 1; d2 < 8; d2 <<= 1) mxv = fmaxf(mxv, __shfl_xor(mxv, d2));
  float e = __expf(s - mxv);
  float sum = e;
#pragma unroll
  for (int d2 = 1; d2 < 8; d2 <<= 1) sum += __shfl_xor(sum, d2);
  Ps[wid][ri][c8] = e / sum;
  __syncthreads();

  const int d = lane;
#pragma unroll
  for (int ii = 0; ii < 8; ++ii) {
    float o = 0.f;
#pragma unroll
    for (int j = 0; j < 8; ++j) o += Ps[wid][ii][j] * (float)Vl[wid][j][d];
    outt[((size_t)(ii * 196 + p) * 8 + bb) * 512 + h * 64 + d] = (bf16)o;
  }
}

// ---------------------------------------------------------------------------
extern "C" void kernel_launch(void* const* d_in, const int* in_sizes, int n_in,
                              void* d_out, int out_size, void* d_ws,
                              size_t ws_size, hipStream_t stream) {
  (void)in_sizes; (void)n_in; (void)out_size; (void)ws_size;
  const float* q    = (const float*)d_in[0];
  const float* win  = (const float*)d_in[3];
  const float* bin  = (const float*)d_in[4];
  const float* wout = (const float*)d_in[5];
  const float* bout = (const float*)d_in[6];
  float* out0 = (float*)d_out;
  float* attn = out0 + 6426624L;   // 1569*8*512

  // ws layout (exactly 64,749,568 bytes):
  bf16* Qh   = (bf16*)d_ws;                 // 12544*512
  bf16* Kh   = Qh + 6422528L;               // 12544*512
  bf16* outs = Kh + 6422528L;               // 8*8*196*8*64
  bf16* outt = outs + 6422528L;             // 12544*512
  bf16* wob  = outt + 6422528L;             // 512*512
  bf16* xb   = wob + 262144L;               // 12544*512

  // wqb scratch in out0 (rows 1..97): GEMM2 (last) overwrites it
  bf16* wqb = (bf16*)(out0 + 4096);         // 1536*512

  prep_kernel<<<7300, 256, 0, stream>>>(q, win, wout, out0, xb, wqb, wob);
  spatial_fused<<<512, 1024, 0, stream>>>(xb, wqb, bin, Qh, Kh, attn, outs);
  temporal_attn<<<3136, 256, 0, stream>>>(Qh, Kh, outs, outt);
  gemm_bt<<<dim3(4, 98), 256, 0, stream>>>(outt, wob, bout, out0, 512, 512,
                                           4096);
}

// Round 18
// 92.015 us; speedup vs baseline: 1.6638x; 1.6638x over previous
//
#include <hip/hip_runtime.h>
#include <cstdint>
#include <cstddef>

typedef __bf16 bf16;
typedef __bf16 bf16x8 __attribute__((ext_vector_type(8)));
typedef __bf16 bf16x4 __attribute__((ext_vector_type(4)));
typedef float  f32x4  __attribute__((ext_vector_type(4)));

#define MFMA16(a, b, c) __builtin_amdgcn_mfma_f32_16x16x32_bf16(a, b, c, 0, 0, 0)

// async global->LDS, 16B per lane, dest = wave-uniform base + lane*16
__device__ __forceinline__ void gl2lds16(const bf16* g, bf16* l) {
  __builtin_amdgcn_global_load_lds(
      (const __attribute__((address_space(1))) void*)g,
      (__attribute__((address_space(3))) void*)l, 16, 0, 0);
}

// ---------------------------------------------------------------------------
// prep: f32 -> bf16 casts (x, W_in, W_out) + q_cls passthrough copy.
// ---------------------------------------------------------------------------
__device__ __forceinline__ void cvt4(const float* __restrict__ s, bf16* __restrict__ d) {
  f32x4 v = *(const f32x4*)s;
  bf16x4 o;
  o[0] = (bf16)v[0]; o[1] = (bf16)v[1]; o[2] = (bf16)v[2]; o[3] = (bf16)v[3];
  *(bf16x4*)d = o;
}

__global__ __launch_bounds__(256) void prep_kernel(
    const float* __restrict__ q, const float* __restrict__ win,
    const float* __restrict__ wout, float* __restrict__ out0,
    bf16* __restrict__ xb, bf16* __restrict__ wqb, bf16* __restrict__ wob) {
  long u = (long)blockIdx.x * 256 + threadIdx.x;
  const long NX4 = 1605632, NWQ4 = 196608, NWO4 = 65536, NQC4 = 1024;
  if (u < NX4) { cvt4(q + 4096 + u * 4, xb + u * 4); return; }
  u -= NX4;
  if (u < NWQ4) { cvt4(win + u * 4, wqb + u * 4); return; }
  u -= NWQ4;
  if (u < NWO4) { cvt4(wout + u * 4, wob + u * 4); return; }
  u -= NWO4;
  if (u < NQC4) { *(f32x4*)(out0 + u * 4) = *(const f32x4*)(q + u * 4); }
}

// ---------------------------------------------------------------------------
// GEMM2: C = A B^T + bias, f32 NT output. 128x128, BK=64, XOR-swizzle.
// ---------------------------------------------------------------------------
__global__ __launch_bounds__(256) void gemm_bt(
    const bf16* __restrict__ A, const bf16* __restrict__ Bm,
    const float* __restrict__ bias, float* __restrict__ Cf,
    int N, int K, long coff) {
  __shared__ bf16 As[128 * 64];
  __shared__ bf16 Bs[128 * 64];
  const int tid = threadIdx.x;
  const int wid = tid >> 6, lane = tid & 63;
  const int lr = lane & 15, lg = lane >> 4;

  const int nwg = gridDim.x * gridDim.y;
  const int orig = blockIdx.y * gridDim.x + blockIdx.x;
  const int cpx = nwg >> 3;
  const int swz = (orig & 7) * cpx + (orig >> 3);
  const int m0 = (swz / gridDim.x) * 128;
  const int n0 = (swz % gridDim.x) * 128;

  const int wr = wid >> 1, wc = wid & 1;
  const int slot = lane & 7, r8 = lane >> 3;
  const int chunk = slot ^ r8;
  const int x7 = lr & 7;

  f32x4 acc[4][4] = {};

  for (int kt = 0; kt < K; kt += 64) {
    __syncthreads();
#pragma unroll
    for (int j = 0; j < 4; ++j) {
      int blk = wid * 4 + j;
      int row = blk * 8 + r8;
      gl2lds16(A + (size_t)(m0 + row) * K + kt + chunk * 8, As + blk * 512);
      gl2lds16(Bm + (size_t)(n0 + row) * K + kt + chunk * 8, Bs + blk * 512);
    }
    __syncthreads();

#pragma unroll
    for (int kk = 0; kk < 2; ++kk) {
      bf16x8 af[4], bfr[4];
#pragma unroll
      for (int m = 0; m < 4; ++m)
        af[m] = *(const bf16x8*)(As + (wr * 64 + m * 16 + lr) * 64 +
                                 (((kk * 4 + lg) ^ x7) * 8));
#pragma unroll
      for (int n = 0; n < 4; ++n)
        bfr[n] = *(const bf16x8*)(Bs + (wc * 64 + n * 16 + lr) * 64 +
                                  (((kk * 4 + lg) ^ x7) * 8));
#pragma unroll
      for (int m = 0; m < 4; ++m)
#pragma unroll
        for (int n = 0; n < 4; ++n)
          acc[m][n] = MFMA16(af[m], bfr[n], acc[m][n]);
    }
  }

#pragma unroll
  for (int m = 0; m < 4; ++m) {
    int row = m0 + wr * 64 + m * 16 + lg * 4;
#pragma unroll
    for (int n = 0; n < 4; ++n) {
      int col = n0 + wc * 64 + n * 16 + lr;
      float bv = bias[col];
#pragma unroll
      for (int i = 0; i < 4; ++i)
        __builtin_nontemporal_store(
            acc[m][n][i] + bv, Cf + coff + (size_t)(row + i) * N + col);
    }
  }
}

// ---------------------------------------------------------------------------
// FUSED spatial (r16 structure + double-buffered phase-1 staging).
// r17's direct-L2 fragment loads were uncoalesced (16 rows/instr) -> 122us;
// REVERTED to r16's LDS staging. New: T3 minimum 2-phase — stage tile t+1
// into the ALTERNATE buffer while computing tile t, ONE barrier per K-step
// (8 vs 16 barrier+vmcnt drains). buf1 overlays Kl+Vt (dead during the kt
// loop; written only in the epilogue, after the final barrier). All layout
// derived from one SMEM array. Vt pad-zero moved after the loop.
// ---------------------------------------------------------------------------
__global__ __launch_bounds__(1024) void spatial_fused(
    const bf16* __restrict__ xb, const bf16* __restrict__ wqb,
    const float* __restrict__ bin, bf16* __restrict__ Qh,
    bf16* __restrict__ Kh, float* __restrict__ attn_out,
    bf16* __restrict__ outs) {
  __shared__ bf16 SMEM[71744];        // 143,488 B total
  bf16* const Kl   = SMEM;            // [0, 16128)        224 x 72
  bf16* const Vt   = SMEM + 16128;    // [16128, 30976)    64 x 232
  bf16* const RB   = SMEM + 30976;    // [30976, 71744)    40768 elems
  bf16* const Qb   = RB + 25600;      // 13x16x72 = 14976  (phase-1 tail)
  bf16* const StgB = RB;              // phase 2: 13x3136 = 40768
  bf16* const bufA = RB;              // kt-loop buf0: X 13312 + W 12288
  bf16* const bufB = SMEM;            // kt-loop buf1: overlays Kl+Vt[0..9472)

  const int tid = threadIdx.x;
  const int wid = tid >> 6, lane = tid & 63;
  const int lr = lane & 15, lg = lane >> 4;
  const int batch = blockIdx.x;            // h*64 + bb*8 + ti
  const int h = batch >> 6;
  const int bb = (batch >> 3) & 7;
  const int ti = batch & 7;

  const int r8 = lane >> 3, slot = lane & 7;
  const int chunk = slot ^ r8;
  const int x7 = lr & 7;

  // ================= phase 1: QKV projection, dbuf staging ==============
  const int qg = wid >> 2, ng = wid & 3;
  const int nfb = ng * 3;
  f32x4 acc[4][3] = {};

  // 50 staging tasks: 0..25 X rows (8 each, clamp 195), 26..49 W rows
  auto STAGE = [&](bf16* dst, int kt) {
#pragma unroll
    for (int t = 0; t < 4; ++t) {
      int task = wid + t * 16;
      if (task < 26) {
        int row = task * 8 + r8;
        int xr = row > 195 ? 195 : row;
        gl2lds16(xb + ((size_t)(ti * 196 + xr) * 8 + bb) * 512 + kt +
                     chunk * 8,
                 dst + task * 512);
      } else if (task < 50) {
        int j = task - 26;
        int strip = j >> 3;                  // 0:Q 1:K 2:V
        int wrow = strip * 512 + h * 64 + (j & 7) * 8 + r8;
        gl2lds16(wqb + (size_t)wrow * 512 + kt + chunk * 8,
                 dst + 13312 + j * 512);
      }
    }
  };

  STAGE(bufA, 0);
  __syncthreads();                      // bufA staged (vmcnt drained)
#pragma unroll
  for (int t = 0; t < 8; ++t) {
    bf16* const cur = (t & 1) ? bufB : bufA;
    if (t < 7) STAGE((t & 1) ? bufA : bufB, (t + 1) * 64);
#pragma unroll
    for (int kk = 0; kk < 2; ++kk) {
      const int xoff = ((kk * 4 + lg) ^ x7) * 8;
      bf16x8 af[4];
#pragma unroll
      for (int qi = 0; qi < 4; ++qi)
        af[qi] = *(const bf16x8*)(cur + ((qg * 4 + qi) * 16 + lr) * 64 + xoff);
#pragma unroll
      for (int nj = 0; nj < 3; ++nj) {
        bf16x8 bfr = *(const bf16x8*)(cur + 13312 +
                                      ((nfb + nj) * 16 + lr) * 64 + xoff);
#pragma unroll
        for (int qi = 0; qi < 4; ++qi)
          acc[qi][nj] = MFMA16(af[qi], bfr, acc[qi][nj]);
      }
    }
    __syncthreads();   // next buf staged AND all reads of cur complete
  }

  // zero Vt pad rows 208..223 (bufB is dead now)
  { int d = tid >> 4, r = 208 + (tid & 15); Vt[d * 232 + r] = (bf16)0.f; }

  // ---- epilogue: bias + repack to Kl/Vt/Qb (all writes guarded qt<13)
#pragma unroll
  for (int qi = 0; qi < 4; ++qi) {
    const int qtg = qg * 4 + qi;
    if (qtg < 13) {
#pragma unroll
      for (int nj = 0; nj < 3; ++nj) {
        const int nf = nfb + nj;             // wave-uniform
        const int strip = nf >> 2;
        float bv = bin[strip * 512 + h * 64 + (nf & 3) * 16 + lr];
        f32x4 a = acc[qi][nj];
#pragma unroll
        for (int i = 0; i < 4; ++i) a[i] += bv;
        if (strip == 0) {
          bf16* qb = Qb + qtg * 1152;
#pragma unroll
          for (int i = 0; i < 4; ++i)
            qb[(lg * 4 + i) * 72 + (nf & 3) * 16 + lr] = (bf16)a[i];
        } else if (strip == 1) {
#pragma unroll
          for (int i = 0; i < 4; ++i)
            Kl[(qtg * 16 + lg * 4 + i) * 72 + (nf & 3) * 16 + lr] =
                (bf16)a[i];
        } else {
          union { bf16x4 h4; uint2 u; } pk;
          pk.h4[0] = (bf16)a[0]; pk.h4[1] = (bf16)a[1];
          pk.h4[2] = (bf16)a[2]; pk.h4[3] = (bf16)a[3];
          int d = (nf & 3) * 16 + lr;
          *(uint2*)&Vt[d * 232 + qtg * 16 + lg * 4] = pk.u;
        }
      }
    }
  }
  __syncthreads();   // Kl/Vt/Qb complete

  // ---- aq read + slab export (cross-wave Qb/Kl reads)
  const int qt = wid;
  bf16x8 aq[2];
  if (qt < 13) {
    const bf16* qb = Qb + qt * 1152;
#pragma unroll
    for (int kk = 0; kk < 2; ++kk)
      aq[kk] = *(const bf16x8*)(qb + lr * 72 + kk * 32 + lg * 8);
    bf16* slabQ = Qh + (size_t)batch * 12544;
    bf16* slabK = Kh + (size_t)batch * 12544;
    const int erow = lane >> 3, eseg = lane & 7;
#pragma unroll
    for (int t = 0; t < 2; ++t) {
      int row = qt * 16 + t * 8 + erow;
      if (row < 196) {
        *(bf16x8*)(slabQ + row * 64 + eseg * 8) =
            *(const bf16x8*)(qb + (t * 8 + erow) * 72 + eseg * 8);
        *(bf16x8*)(slabK + row * 64 + eseg * 8) =
            *(const bf16x8*)(Kl + row * 72 + eseg * 8);
      }
    }
  }
  __syncthreads();   // Qb dead -> StgB may clobber

  // ================= phase 2: attention =================
  if (qt < 13) {
    const int q = qt * 16 + lr;

    f32x4 s[14] = {};
    __builtin_amdgcn_s_setprio(1);
#pragma unroll
    for (int nn = 0; nn < 14; ++nn) {
      const int krow = nn * 16 + lr;
      bf16x8 bk0 = *(const bf16x8*)&Kl[krow * 72 + lg * 8];
      bf16x8 bk1 = *(const bf16x8*)&Kl[krow * 72 + 32 + lg * 8];
      s[nn] = MFMA16(bk0, aq[0], s[nn]);
      s[nn] = MFMA16(bk1, aq[1], s[nn]);
    }
    __builtin_amdgcn_s_setprio(0);

#pragma unroll
    for (int nn = 0; nn < 14; ++nn) {
      bool pad = (nn * 16 + lg * 4 >= 196);
#pragma unroll
      for (int i = 0; i < 4; ++i)
        s[nn][i] = pad ? -1e30f : s[nn][i] * 0.125f;
    }

    float v = -1e30f;
#pragma unroll
    for (int nn = 0; nn < 14; ++nn)
#pragma unroll
      for (int i = 0; i < 4; ++i) v = fmaxf(v, s[nn][i]);
    v = fmaxf(v, __shfl_xor(v, 16));
    v = fmaxf(v, __shfl_xor(v, 32));
    float sum = 0.f;
#pragma unroll
    for (int nn = 0; nn < 14; ++nn)
#pragma unroll
      for (int i = 0; i < 4; ++i) {
        float e = __expf(s[nn][i] - v);
        s[nn][i] = e;
        sum += e;
      }
    sum += __shfl_xor(sum, 16);
    sum += __shfl_xor(sum, 32);
    const float rinv = 1.f / sum;

    bf16* const tile = StgB + qt * 3136;
    const int low = lr + 32 * (lg & 1);
    const int high = low + 16;
    const bool hiN = (lg >> 1) != 0;
    f32x4 o[4] = {};
#pragma unroll
    for (int kb = 0; kb < 7; ++kb) {
      uint32_t px[2], py[2];
#pragma unroll
      for (int t = 0; t < 2; ++t) {
        const int nn = 2 * kb + t;
        f32x4 sv;
#pragma unroll
        for (int i = 0; i < 4; ++i) sv[i] = s[nn][i] * rinv;
        union { bf16x4 h4; uint2 u; } pk;
        pk.h4[0] = (bf16)sv[0]; pk.h4[1] = (bf16)sv[1];
        pk.h4[2] = (bf16)sv[2]; pk.h4[3] = (bf16)sv[3];
        int kbase = nn * 16 + lg * 4;
        if (kbase < 196)
          *(uint2*)((char*)tile + lr * 392 + kbase * 2) = pk.u;
        px[t] = pk.u.x; py[t] = pk.u.y;
      }
      uint32_t a0x = __shfl((int)px[0], low);
      uint32_t a0y = __shfl((int)py[0], low);
      uint32_t a1x = __shfl((int)px[1], low);
      uint32_t a1y = __shfl((int)py[1], low);
      uint32_t b0x = __shfl((int)px[0], high);
      uint32_t b0y = __shfl((int)py[0], high);
      uint32_t b1x = __shfl((int)px[1], high);
      uint32_t b1y = __shfl((int)py[1], high);
      union { uint32_t u[4]; bf16x8 h8; } pa;
      pa.u[0] = hiN ? a1x : a0x;
      pa.u[1] = hiN ? a1y : a0y;
      pa.u[2] = hiN ? b1x : b0x;
      pa.u[3] = hiN ? b1y : b0y;
      __builtin_amdgcn_s_setprio(1);
#pragma unroll
      for (int nd = 0; nd < 4; ++nd) {
        bf16x8 vb = *(const bf16x8*)&Vt[(nd * 16 + lr) * 232 + kb * 32 + lg * 8];
        o[nd] = MFMA16(pa.h8, vb, o[nd]);
      }
      __builtin_amdgcn_s_setprio(0);
    }

    // write out_s in v_t layout [h][bb][p][ti][d]
    {
      const int hb8 = batch >> 3;
#pragma unroll
      for (int i = 0; i < 4; ++i) {
        int p = qt * 16 + lg * 4 + i;
        if (p < 196) {
#pragma unroll
          for (int nd = 0; nd < 4; ++nd) {
            int d = nd * 16 + lr;
            outs[(((size_t)(hb8 * 196 + p)) * 8 + ti) * 64 + d] =
                (bf16)o[nd][i];
          }
        }
      }
    }

    // aligned copy-out: LDS bf16 stripe -> global f32 (exact bit expand)
    {
      const int vbytes = (qt == 12) ? 3136 : 12544;
      char* dst = (char*)(attn_out + (size_t)batch * 38416 + qt * 3136);
      const char* src = (const char*)tile;
#pragma unroll
      for (int j = 0; j < 13; ++j) {
        int x = j * 1024 + lane * 16;
        if (x < vbytes) {
          uint2 u = *(const uint2*)(src + (x >> 1));
          union { uint32_t b; float f; } c0, c1, c2, c3;
          c0.b = (u.x & 0xffffu) << 16; c1.b = u.x & 0xffff0000u;
          c2.b = (u.y & 0xffffu) << 16; c3.b = u.y & 0xffff0000u;
          f32x4 ov; ov[0] = c0.f; ov[1] = c1.f; ov[2] = c2.f; ov[3] = c3.f;
          *(f32x4*)(dst + x) = ov;
        }
      }
    }
  }
}

// ---------------------------------------------------------------------------
// Temporal attention: 1 wave per (h, bb, p) batch; t=8, dh=64.
// ---------------------------------------------------------------------------
__global__ __launch_bounds__(256) void temporal_attn(
    const bf16* __restrict__ Qh, const bf16* __restrict__ Kh,
    const bf16* __restrict__ outs, bf16* __restrict__ outt) {
  __shared__ bf16 Ql[4][8][72];
  __shared__ bf16 Kc[4][8][72];
  __shared__ bf16 Vl[4][8][64];
  __shared__ float Ps[4][8][8];

  const int tid = threadIdx.x, wid = tid >> 6, lane = tid & 63;
  const int batch = blockIdx.x * 4 + wid;  // (h*8+bb)*196 + p
  const int p = batch % 196;
  const int hb = batch / 196;
  const int bb = hb & 7, h = hb >> 3;

  const int ri = lane >> 3;
  const int c8 = lane & 7;
  {
    size_t so = ((size_t)(h * 64 + bb * 8 + ri)) * 12544 + p * 64 + c8 * 8;
    *(bf16x8*)&Ql[wid][ri][c8 * 8] = *(const bf16x8*)(Qh + so);
    *(bf16x8*)&Kc[wid][ri][c8 * 8] = *(const bf16x8*)(Kh + so);
    *(bf16x8*)&Vl[wid][ri][c8 * 8] =
        *(const bf16x8*)(outs + ((size_t)batch * 8 + ri) * 64 + c8 * 8);
  }
  __syncthreads();

  float s = 0.f;
#pragma unroll
  for (int d = 0; d < 64; d += 8) {
    bf16x8 qv = *(const bf16x8*)&Ql[wid][ri][d];
    bf16x8 kv = *(const bf16x8*)&Kc[wid][c8][d];
#pragma unroll
    for (int e = 0; e < 8; ++e) s += (float)qv[e] * (float)kv[e];
  }
  s *= 0.125f;
  float mxv = s;
#pragma unroll
  for (int d2 = 1; d2 < 8; d2 <<= 1) mxv = fmaxf(mxv, __shfl_xor(mxv, d2));
  float e = __expf(s - mxv);
  float sum = e;
#pragma unroll
  for (int d2 = 1; d2 < 8; d2 <<= 1) sum += __shfl_xor(sum, d2);
  Ps[wid][ri][c8] = e / sum;
  __syncthreads();

  const int d = lane;
#pragma unroll
  for (int ii = 0; ii < 8; ++ii) {
    float o = 0.f;
#pragma unroll
    for (int j = 0; j < 8; ++j) o += Ps[wid][ii][j] * (float)Vl[wid][j][d];
    outt[((size_t)(ii * 196 + p) * 8 + bb) * 512 + h * 64 + d] = (bf16)o;
  }
}

// ---------------------------------------------------------------------------
extern "C" void kernel_launch(void* const* d_in, const int* in_sizes, int n_in,
                              void* d_out, int out_size, void* d_ws,
                              size_t ws_size, hipStream_t stream) {
  (void)in_sizes; (void)n_in; (void)out_size; (void)ws_size;
  const float* q    = (const float*)d_in[0];
  const float* win  = (const float*)d_in[3];
  const float* bin  = (const float*)d_in[4];
  const float* wout = (const float*)d_in[5];
  const float* bout = (const float*)d_in[6];
  float* out0 = (float*)d_out;
  float* attn = out0 + 6426624L;   // 1569*8*512

  // ws layout (exactly 64,749,568 bytes):
  bf16* Qh   = (bf16*)d_ws;                 // 12544*512
  bf16* Kh   = Qh + 6422528L;               // 12544*512
  bf16* outs = Kh + 6422528L;               // 8*8*196*8*64
  bf16* outt = outs + 6422528L;             // 12544*512
  bf16* wob  = outt + 6422528L;             // 512*512
  bf16* xb   = wob + 262144L;               // 12544*512

  // wqb scratch in out0 (rows 1..97): GEMM2 (last) overwrites it
  bf16* wqb = (bf16*)(out0 + 4096);         // 1536*512

  prep_kernel<<<7300, 256, 0, stream>>>(q, win, wout, out0, xb, wqb, wob);
  spatial_fused<<<512, 1024, 0, stream>>>(xb, wqb, bin, Qh, Kh, attn, outs);
  temporal_attn<<<3136, 256, 0, stream>>>(Qh, Kh, outs, outt);
  gemm_bt<<<dim3(4, 98), 256, 0, stream>>>(outt, wob, bout, out0, 512, 512,
                                           4096);
}

// Round 19
// 89.267 us; speedup vs baseline: 1.7150x; 1.0308x over previous
//
#include <hip/hip_runtime.h>
#include <cstdint>
#include <cstddef>

typedef __bf16 bf16;
typedef __bf16 bf16x8 __attribute__((ext_vector_type(8)));
typedef __bf16 bf16x4 __attribute__((ext_vector_type(4)));
typedef float  f32x4  __attribute__((ext_vector_type(4)));

#define MFMA16(a, b, c) __builtin_amdgcn_mfma_f32_16x16x32_bf16(a, b, c, 0, 0, 0)

// async global->LDS, 16B per lane, dest = wave-uniform base + lane*16
__device__ __forceinline__ void gl2lds16(const bf16* g, bf16* l) {
  __builtin_amdgcn_global_load_lds(
      (const __attribute__((address_space(1))) void*)g,
      (__attribute__((address_space(3))) void*)l, 16, 0, 0);
}

// ---------------------------------------------------------------------------
// prep: f32 -> bf16 casts (x, W_in, W_out) + q_cls passthrough copy.
// ---------------------------------------------------------------------------
__device__ __forceinline__ void cvt4(const float* __restrict__ s, bf16* __restrict__ d) {
  f32x4 v = *(const f32x4*)s;
  bf16x4 o;
  o[0] = (bf16)v[0]; o[1] = (bf16)v[1]; o[2] = (bf16)v[2]; o[3] = (bf16)v[3];
  *(bf16x4*)d = o;
}

__global__ __launch_bounds__(256) void prep_kernel(
    const float* __restrict__ q, const float* __restrict__ win,
    const float* __restrict__ wout, float* __restrict__ out0,
    bf16* __restrict__ xb, bf16* __restrict__ wqb, bf16* __restrict__ wob) {
  long u = (long)blockIdx.x * 256 + threadIdx.x;
  const long NX4 = 1605632, NWQ4 = 196608, NWO4 = 65536, NQC4 = 1024;
  if (u < NX4) { cvt4(q + 4096 + u * 4, xb + u * 4); return; }
  u -= NX4;
  if (u < NWQ4) { cvt4(win + u * 4, wqb + u * 4); return; }
  u -= NWQ4;
  if (u < NWO4) { cvt4(wout + u * 4, wob + u * 4); return; }
  u -= NWO4;
  if (u < NQC4) { *(f32x4*)(out0 + u * 4) = *(const f32x4*)(q + u * 4); }
}

// ---------------------------------------------------------------------------
// GEMM2: C = A B^T + bias, f32 NT output. 128x128, BK=64, XOR-swizzle.
// ---------------------------------------------------------------------------
__global__ __launch_bounds__(256) void gemm_bt(
    const bf16* __restrict__ A, const bf16* __restrict__ Bm,
    const float* __restrict__ bias, float* __restrict__ Cf,
    int N, int K, long coff) {
  __shared__ bf16 As[128 * 64];
  __shared__ bf16 Bs[128 * 64];
  const int tid = threadIdx.x;
  const int wid = tid >> 6, lane = tid & 63;
  const int lr = lane & 15, lg = lane >> 4;

  const int nwg = gridDim.x * gridDim.y;
  const int orig = blockIdx.y * gridDim.x + blockIdx.x;
  const int cpx = nwg >> 3;
  const int swz = (orig & 7) * cpx + (orig >> 3);
  const int m0 = (swz / gridDim.x) * 128;
  const int n0 = (swz % gridDim.x) * 128;

  const int wr = wid >> 1, wc = wid & 1;
  const int slot = lane & 7, r8 = lane >> 3;
  const int chunk = slot ^ r8;
  const int x7 = lr & 7;

  f32x4 acc[4][4] = {};

  for (int kt = 0; kt < K; kt += 64) {
    __syncthreads();
#pragma unroll
    for (int j = 0; j < 4; ++j) {
      int blk = wid * 4 + j;
      int row = blk * 8 + r8;
      gl2lds16(A + (size_t)(m0 + row) * K + kt + chunk * 8, As + blk * 512);
      gl2lds16(Bm + (size_t)(n0 + row) * K + kt + chunk * 8, Bs + blk * 512);
    }
    __syncthreads();

#pragma unroll
    for (int kk = 0; kk < 2; ++kk) {
      bf16x8 af[4], bfr[4];
#pragma unroll
      for (int m = 0; m < 4; ++m)
        af[m] = *(const bf16x8*)(As + (wr * 64 + m * 16 + lr) * 64 +
                                 (((kk * 4 + lg) ^ x7) * 8));
#pragma unroll
      for (int n = 0; n < 4; ++n)
        bfr[n] = *(const bf16x8*)(Bs + (wc * 64 + n * 16 + lr) * 64 +
                                  (((kk * 4 + lg) ^ x7) * 8));
#pragma unroll
      for (int m = 0; m < 4; ++m)
#pragma unroll
        for (int n = 0; n < 4; ++n)
          acc[m][n] = MFMA16(af[m], bfr[n], acc[m][n]);
    }
  }

#pragma unroll
  for (int m = 0; m < 4; ++m) {
    int row = m0 + wr * 64 + m * 16 + lg * 4;
#pragma unroll
    for (int n = 0; n < 4; ++n) {
      int col = n0 + wc * 64 + n * 16 + lr;
      float bv = bias[col];
#pragma unroll
      for (int i = 0; i < 4; ++i)
        __builtin_nontemporal_store(
            acc[m][n][i] + bv, Cf + coff + (size_t)(row + i) * N + col);
    }
  }
}

// ---------------------------------------------------------------------------
// FUSED spatial (r16, measured optimum 89.7us). Phase 1: QKV projection with
// 4x4 wave grid (wave (qg,ng) owns 4 q-tiles x 3 nf-frags; 14 ds_reads/iter)
// staged per-BK=64 via gl2lds + XOR-involution swizzle. Phase 2: swapped-QK^T
// attention with in-register softmax, StgB-realigned attn stores.
// r17 (direct-L2 frags, uncoalesced) and r18 (explicit dbuf) both regressed.
// ---------------------------------------------------------------------------
__global__ __launch_bounds__(1024) void spatial_fused(
    const bf16* __restrict__ xb, const bf16* __restrict__ wqb,
    const float* __restrict__ bin, bf16* __restrict__ Qh,
    bf16* __restrict__ Kh, float* __restrict__ attn_out,
    bf16* __restrict__ outs) {
  __shared__ bf16 Kl[224 * 72];       // [k-row][72]
  __shared__ bf16 Vt[64 * 232];       // [d][k-row]
  __shared__ bf16 RB[40768];          // union region
  bf16* const Xs  = RB;               // [0, 13312)   208x64
  bf16* const Wss = RB + 13312;       // [13312, 25600) 192x64
  bf16* const Qb  = RB + 25600;       // [25600, 40576) 13x16x72
  bf16* const StgB = RB;              // phase 2: 13x3136

  const int tid = threadIdx.x;
  const int wid = tid >> 6, lane = tid & 63;
  const int lr = lane & 15, lg = lane >> 4;
  const int batch = blockIdx.x;            // h*64 + bb*8 + ti
  const int h = batch >> 6;
  const int bb = (batch >> 3) & 7;
  const int ti = batch & 7;

  // zero Vt pad rows 208..223
  { int d = tid >> 4, r = 208 + (tid & 15); Vt[d * 232 + r] = (bf16)0.f; }

  const int r8 = lane >> 3, slot = lane & 7;
  const int chunk = slot ^ r8;
  const int x7 = lr & 7;

  // ================= phase 1: QKV projection, 4x4 wave grid =============
  const int qg = wid >> 2, ng = wid & 3;
  const int nfb = ng * 3;
  f32x4 acc[4][3] = {};

  for (int kt = 0; kt < 512; kt += 64) {
    __syncthreads();
#pragma unroll
    for (int t = 0; t < 4; ++t) {
      int task = wid + t * 16;
      if (task < 26) {
        int row = task * 8 + r8;
        int xr = row > 195 ? 195 : row;
        gl2lds16(xb + ((size_t)(ti * 196 + xr) * 8 + bb) * 512 + kt +
                     chunk * 8,
                 Xs + task * 512);
      } else if (task < 50) {
        int j = task - 26;
        int strip = j >> 3;                  // 0:Q 1:K 2:V
        int wrow = strip * 512 + h * 64 + (j & 7) * 8 + r8;
        gl2lds16(wqb + (size_t)wrow * 512 + kt + chunk * 8, Wss + j * 512);
      }
    }
    __syncthreads();
#pragma unroll
    for (int kk = 0; kk < 2; ++kk) {
      const int xoff = ((kk * 4 + lg) ^ x7) * 8;
      bf16x8 af[4];
#pragma unroll
      for (int qi = 0; qi < 4; ++qi)
        af[qi] = *(const bf16x8*)(Xs + ((qg * 4 + qi) * 16 + lr) * 64 + xoff);
#pragma unroll
      for (int nj = 0; nj < 3; ++nj) {
        bf16x8 bfr = *(const bf16x8*)(Wss + ((nfb + nj) * 16 + lr) * 64 + xoff);
#pragma unroll
        for (int qi = 0; qi < 4; ++qi)
          acc[qi][nj] = MFMA16(af[qi], bfr, acc[qi][nj]);
      }
    }
  }

  // ---- epilogue: bias + repack to Kl/Vt/Qb (all writes guarded qt<13)
#pragma unroll
  for (int qi = 0; qi < 4; ++qi) {
    const int qtg = qg * 4 + qi;
    if (qtg < 13) {
#pragma unroll
      for (int nj = 0; nj < 3; ++nj) {
        const int nf = nfb + nj;             // wave-uniform
        const int strip = nf >> 2;
        float bv = bin[strip * 512 + h * 64 + (nf & 3) * 16 + lr];
        f32x4 a = acc[qi][nj];
#pragma unroll
        for (int i = 0; i < 4; ++i) a[i] += bv;
        if (strip == 0) {
          bf16* qb = Qb + qtg * 1152;
#pragma unroll
          for (int i = 0; i < 4; ++i)
            qb[(lg * 4 + i) * 72 + (nf & 3) * 16 + lr] = (bf16)a[i];
        } else if (strip == 1) {
#pragma unroll
          for (int i = 0; i < 4; ++i)
            Kl[(qtg * 16 + lg * 4 + i) * 72 + (nf & 3) * 16 + lr] =
                (bf16)a[i];
        } else {
          union { bf16x4 h4; uint2 u; } pk;
          pk.h4[0] = (bf16)a[0]; pk.h4[1] = (bf16)a[1];
          pk.h4[2] = (bf16)a[2]; pk.h4[3] = (bf16)a[3];
          int d = (nf & 3) * 16 + lr;
          *(uint2*)&Vt[d * 232 + qtg * 16 + lg * 4] = pk.u;
        }
      }
    }
  }
  __syncthreads();   // Kl/Vt/Qb complete

  // ---- aq read + slab export (cross-wave Qb/Kl reads)
  const int qt = wid;
  bf16x8 aq[2];
  if (qt < 13) {
    const bf16* qb = Qb + qt * 1152;
#pragma unroll
    for (int kk = 0; kk < 2; ++kk)
      aq[kk] = *(const bf16x8*)(qb + lr * 72 + kk * 32 + lg * 8);
    bf16* slabQ = Qh + (size_t)batch * 12544;
    bf16* slabK = Kh + (size_t)batch * 12544;
    const int erow = lane >> 3, eseg = lane & 7;
#pragma unroll
    for (int t = 0; t < 2; ++t) {
      int row = qt * 16 + t * 8 + erow;
      if (row < 196) {
        *(bf16x8*)(slabQ + row * 64 + eseg * 8) =
            *(const bf16x8*)(qb + (t * 8 + erow) * 72 + eseg * 8);
        *(bf16x8*)(slabK + row * 64 + eseg * 8) =
            *(const bf16x8*)(Kl + row * 72 + eseg * 8);
      }
    }
  }
  __syncthreads();   // Qb dead -> StgB may clobber

  // ================= phase 2: attention =================
  if (qt < 13) {
    const int q = qt * 16 + lr;

    f32x4 s[14] = {};
    __builtin_amdgcn_s_setprio(1);
#pragma unroll
    for (int nn = 0; nn < 14; ++nn) {
      const int krow = nn * 16 + lr;
      bf16x8 bk0 = *(const bf16x8*)&Kl[krow * 72 + lg * 8];
      bf16x8 bk1 = *(const bf16x8*)&Kl[krow * 72 + 32 + lg * 8];
      s[nn] = MFMA16(bk0, aq[0], s[nn]);
      s[nn] = MFMA16(bk1, aq[1], s[nn]);
    }
    __builtin_amdgcn_s_setprio(0);

#pragma unroll
    for (int nn = 0; nn < 14; ++nn) {
      bool pad = (nn * 16 + lg * 4 >= 196);
#pragma unroll
      for (int i = 0; i < 4; ++i)
        s[nn][i] = pad ? -1e30f : s[nn][i] * 0.125f;
    }

    float v = -1e30f;
#pragma unroll
    for (int nn = 0; nn < 14; ++nn)
#pragma unroll
      for (int i = 0; i < 4; ++i) v = fmaxf(v, s[nn][i]);
    v = fmaxf(v, __shfl_xor(v, 16));
    v = fmaxf(v, __shfl_xor(v, 32));
    float sum = 0.f;
#pragma unroll
    for (int nn = 0; nn < 14; ++nn)
#pragma unroll
      for (int i = 0; i < 4; ++i) {
        float e = __expf(s[nn][i] - v);
        s[nn][i] = e;
        sum += e;
      }
    sum += __shfl_xor(sum, 16);
    sum += __shfl_xor(sum, 32);
    const float rinv = 1.f / sum;

    bf16* const tile = StgB + qt * 3136;
    const int low = lr + 32 * (lg & 1);
    const int high = low + 16;
    const bool hiN = (lg >> 1) != 0;
    f32x4 o[4] = {};
#pragma unroll
    for (int kb = 0; kb < 7; ++kb) {
      uint32_t px[2], py[2];
#pragma unroll
      for (int t = 0; t < 2; ++t) {
        const int nn = 2 * kb + t;
        f32x4 sv;
#pragma unroll
        for (int i = 0; i < 4; ++i) sv[i] = s[nn][i] * rinv;
        union { bf16x4 h4; uint2 u; } pk;
        pk.h4[0] = (bf16)sv[0]; pk.h4[1] = (bf16)sv[1];
        pk.h4[2] = (bf16)sv[2]; pk.h4[3] = (bf16)sv[3];
        int kbase = nn * 16 + lg * 4;
        if (kbase < 196)
          *(uint2*)((char*)tile + lr * 392 + kbase * 2) = pk.u;
        px[t] = pk.u.x; py[t] = pk.u.y;
      }
      uint32_t a0x = __shfl((int)px[0], low);
      uint32_t a0y = __shfl((int)py[0], low);
      uint32_t a1x = __shfl((int)px[1], low);
      uint32_t a1y = __shfl((int)py[1], low);
      uint32_t b0x = __shfl((int)px[0], high);
      uint32_t b0y = __shfl((int)py[0], high);
      uint32_t b1x = __shfl((int)px[1], high);
      uint32_t b1y = __shfl((int)py[1], high);
      union { uint32_t u[4]; bf16x8 h8; } pa;
      pa.u[0] = hiN ? a1x : a0x;
      pa.u[1] = hiN ? a1y : a0y;
      pa.u[2] = hiN ? b1x : b0x;
      pa.u[3] = hiN ? b1y : b0y;
      __builtin_amdgcn_s_setprio(1);
#pragma unroll
      for (int nd = 0; nd < 4; ++nd) {
        bf16x8 vb = *(const bf16x8*)&Vt[(nd * 16 + lr) * 232 + kb * 32 + lg * 8];
        o[nd] = MFMA16(pa.h8, vb, o[nd]);
      }
      __builtin_amdgcn_s_setprio(0);
    }

    // write out_s in v_t layout [h][bb][p][ti][d]
    {
      const int hb8 = batch >> 3;
#pragma unroll
      for (int i = 0; i < 4; ++i) {
        int p = qt * 16 + lg * 4 + i;
        if (p < 196) {
#pragma unroll
          for (int nd = 0; nd < 4; ++nd) {
            int d = nd * 16 + lr;
            outs[(((size_t)(hb8 * 196 + p)) * 8 + ti) * 64 + d] =
                (bf16)o[nd][i];
          }
        }
      }
    }

    // aligned copy-out: LDS bf16 stripe -> global f32 (exact bit expand)
    {
      const int vbytes = (qt == 12) ? 3136 : 12544;
      char* dst = (char*)(attn_out + (size_t)batch * 38416 + qt * 3136);
      const char* src = (const char*)tile;
#pragma unroll
      for (int j = 0; j < 13; ++j) {
        int x = j * 1024 + lane * 16;
        if (x < vbytes) {
          uint2 u = *(const uint2*)(src + (x >> 1));
          union { uint32_t b; float f; } c0, c1, c2, c3;
          c0.b = (u.x & 0xffffu) << 16; c1.b = u.x & 0xffff0000u;
          c2.b = (u.y & 0xffffu) << 16; c3.b = u.y & 0xffff0000u;
          f32x4 ov; ov[0] = c0.f; ov[1] = c1.f; ov[2] = c2.f; ov[3] = c3.f;
          *(f32x4*)(dst + x) = ov;
        }
      }
    }
  }
}

// ---------------------------------------------------------------------------
// Temporal attention: 1 wave per (h, bb, p) batch; t=8, dh=64.
// ---------------------------------------------------------------------------
__global__ __launch_bounds__(256) void temporal_attn(
    const bf16* __restrict__ Qh, const bf16* __restrict__ Kh,
    const bf16* __restrict__ outs, bf16* __restrict__ outt) {
  __shared__ bf16 Ql[4][8][72];
  __shared__ bf16 Kc[4][8][72];
  __shared__ bf16 Vl[4][8][64];
  __shared__ float Ps[4][8][8];

  const int tid = threadIdx.x, wid = tid >> 6, lane = tid & 63;
  const int batch = blockIdx.x * 4 + wid;  // (h*8+bb)*196 + p
  const int p = batch % 196;
  const int hb = batch / 196;
  const int bb = hb & 7, h = hb >> 3;

  const int ri = lane >> 3;
  const int c8 = lane & 7;
  {
    size_t so = ((size_t)(h * 64 + bb * 8 + ri)) * 12544 + p * 64 + c8 * 8;
    *(bf16x8*)&Ql[wid][ri][c8 * 8] = *(const bf16x8*)(Qh + so);
    *(bf16x8*)&Kc[wid][ri][c8 * 8] = *(const bf16x8*)(Kh + so);
    *(bf16x8*)&Vl[wid][ri][c8 * 8] =
        *(const bf16x8*)(outs + ((size_t)batch * 8 + ri) * 64 + c8 * 8);
  }
  __syncthreads();

  float s = 0.f;
#pragma unroll
  for (int d = 0; d < 64; d += 8) {
    bf16x8 qv = *(const bf16x8*)&Ql[wid][ri][d];
    bf16x8 kv = *(const bf16x8*)&Kc[wid][c8][d];
#pragma unroll
    for (int e = 0; e < 8; ++e) s += (float)qv[e] * (float)kv[e];
  }
  s *= 0.125f;
  float mxv = s;
#pragma unroll
  for (int d2 = 1; d2 < 8; d2 <<= 1) mxv = fmaxf(mxv, __shfl_xor(mxv, d2));
  float e = __expf(s - mxv);
  float sum = e;
#pragma unroll
  for (int d2 = 1; d2 < 8; d2 <<= 1) sum += __shfl_xor(sum, d2);
  Ps[wid][ri][c8] = e / sum;
  __syncthreads();

  const int d = lane;
#pragma unroll
  for (int ii = 0; ii < 8; ++ii) {
    float o = 0.f;
#pragma unroll
    for (int j = 0; j < 8; ++j) o += Ps[wid][ii][j] * (float)Vl[wid][j][d];
    outt[((size_t)(ii * 196 + p) * 8 + bb) * 512 + h * 64 + d] = (bf16)o;
  }
}

// ---------------------------------------------------------------------------
extern "C" void kernel_launch(void* const* d_in, const int* in_sizes, int n_in,
                              void* d_out, int out_size, void* d_ws,
                              size_t ws_size, hipStream_t stream) {
  (void)in_sizes; (void)n_in; (void)out_size; (void)ws_size;
  const float* q    = (const float*)d_in[0];
  const float* win  = (const float*)d_in[3];
  const float* bin  = (const float*)d_in[4];
  const float* wout = (const float*)d_in[5];
  const float* bout = (const float*)d_in[6];
  float* out0 = (float*)d_out;
  float* attn = out0 + 6426624L;   // 1569*8*512

  // ws layout (exactly 64,749,568 bytes):
  bf16* Qh   = (bf16*)d_ws;                 // 12544*512
  bf16* Kh   = Qh + 6422528L;               // 12544*512
  bf16* outs = Kh + 6422528L;               // 8*8*196*8*64
  bf16* outt = outs + 6422528L;             // 12544*512
  bf16* wob  = outt + 6422528L;             // 512*512
  bf16* xb   = wob + 262144L;               // 12544*512

  // wqb scratch in out0 (rows 1..97): GEMM2 (last) overwrites it
  bf16* wqb = (bf16*)(out0 + 4096);         // 1536*512

  prep_kernel<<<7300, 256, 0, stream>>>(q, win, wout, out0, xb, wqb, wob);
  spatial_fused<<<512, 1024, 0, stream>>>(xb, wqb, bin, Qh, Kh, attn, outs);
  temporal_attn<<<3136, 256, 0, stream>>>(Qh, Kh, outs, outt);
  gemm_bt<<<dim3(4, 98), 256, 0, stream>>>(outt, wob, bout, out0, 512, 512,
                                           4096);
}